// Round 7
// baseline (162.018 us; speedup 1.0000x reference)
//
#include <hip/hip_runtime.h>
#include <math.h>

#define N_SEQ 1024
#define LL 64
#define DH 256
#define DX 128
#define MQ 8192
#define GG 4096
#define NTYP 64
#define NMEM 262144

typedef __attribute__((ext_vector_type(8))) short short8v;
typedef __attribute__((ext_vector_type(4))) float float4v;

__device__ __forceinline__ float bcast(float v, int l) {
    return __uint_as_float(__builtin_amdgcn_readlane(__float_as_uint(v), l));
}

__device__ __forceinline__ unsigned short f2bf(float x) {
    unsigned int u = __float_as_uint(x);
    u += 0x7FFFu + ((u >> 16) & 1u);   // round-to-nearest-even
    return (unsigned short)(u >> 16);
}

// ---------------- counting-sort based segment sum ---------------------------
__global__ __launch_bounds__(256) void k_hist(const int* __restrict__ grp,
                                              int* __restrict__ cnt) {
    int i = blockIdx.x * 256 + threadIdx.x;
    if (i < NMEM) atomicAdd(&cnt[grp[i]], 1);
}

__global__ __launch_bounds__(1024) void k_scan(const int* __restrict__ cnt,
                                               int* __restrict__ ofs,
                                               int* __restrict__ cur) {
    __shared__ int wsum[16];
    int tid = threadIdx.x;
    int4 c = ((const int4*)cnt)[tid];
    int local = c.x + c.y + c.z + c.w;
    int lane = tid & 63, w = tid >> 6;
    int v = local;
    for (int off = 1; off < 64; off <<= 1) {
        int t = __shfl_up(v, off);
        if (lane >= off) v += t;
    }
    if (lane == 63) wsum[w] = v;
    __syncthreads();
    if (tid < 16) {
        int s = wsum[tid];
        for (int off = 1; off < 16; off <<= 1) {
            int t = __shfl_up(s, off);
            if (tid >= off) s += t;
        }
        wsum[tid] = s;
    }
    __syncthreads();
    int base = (w > 0 ? wsum[w - 1] : 0) + (v - local);
    int4 o;
    o.x = base;
    o.y = base + c.x;
    o.z = o.y + c.y;
    o.w = o.z + c.z;
    ((int4*)ofs)[tid] = o;
    ((int4*)cur)[tid] = o;
}

__global__ __launch_bounds__(256) void k_permute(const int* __restrict__ grp,
                                                 const int* __restrict__ mem,
                                                 int* __restrict__ cur,
                                                 int* __restrict__ tok_sorted) {
    int i = blockIdx.x * 256 + threadIdx.x;
    if (i < NMEM) {
        int g = grp[i];
        int pos = atomicAdd(&cur[g], 1);
        tok_sorted[pos] = mem[i];
    }
}

// z[g] = sum tok_emb rows; fused: zw[g] = z[g] @ Wrel[512:640]
__global__ __launch_bounds__(128) void k_zsum(const int* __restrict__ ofs,
                                              const int* __restrict__ cnt,
                                              const int* __restrict__ tok_sorted,
                                              const float* __restrict__ tok_emb,
                                              const float* __restrict__ Wrel,
                                              float* __restrict__ zw) {
    __shared__ int idxs[128];
    __shared__ float zs[128];
    int g = blockIdx.x;
    int tid = threadIdx.x;
    int start = ofs[g], n = cnt[g];
    float acc = 0.f;
    for (int j0 = 0; j0 < n; j0 += 128) {
        __syncthreads();
        int rem = n - j0;
        if (tid < rem) idxs[tid] = tok_sorted[start + j0 + tid];
        __syncthreads();
        int kmax = rem < 128 ? rem : 128;
        for (int k = 0; k < kmax; ++k)
            acc += tok_emb[(size_t)idxs[k] * DX + tid];
    }
    zs[tid] = acc;
    __syncthreads();
    if (tid < NTYP) {
        float a2 = 0.f;
#pragma unroll 8
        for (int v = 0; v < DX; ++v)
            a2 += zs[v] * Wrel[(size_t)(512 + v) * NTYP + tid];
        zw[(size_t)g * NTYP + tid] = a2;
    }
}

// ---------------- build BT[320][512] bf16 and bias[320] ---------------------
__global__ __launch_bounds__(256) void k_wqkb(const float* __restrict__ Wq,
                                              const float* __restrict__ bq,
                                              const float* __restrict__ Wk,
                                              const float* __restrict__ Wrel,
                                              unsigned short* __restrict__ BT,
                                              float* __restrict__ bias) {
    int n = blockIdx.x;
    int tid = threadIdx.x;
    if (n < 256) {
        __shared__ float wk_s[256];
        __shared__ float red[4];
        wk_s[tid] = Wk[(size_t)n * 256 + tid];
        __syncthreads();
#pragma unroll
        for (int jj = 0; jj < 2; ++jj) {
            int j = tid + jj * 256;
            const float* wq = Wq + (size_t)j * 256;
            float acc = 0.f;
#pragma unroll 4
            for (int e = 0; e < 256; ++e) acc += wq[e] * wk_s[e];
            BT[(size_t)n * 512 + j] = f2bf(acc);
        }
        float p = wk_s[tid] * bq[tid];
        for (int o = 32; o; o >>= 1) p += __shfl_xor(p, o);
        if ((tid & 63) == 0) red[tid >> 6] = p;
        __syncthreads();
        if (tid == 0) bias[n] = red[0] + red[1] + red[2] + red[3];
    } else {
        int t = n - 256;
#pragma unroll
        for (int jj = 0; jj < 2; ++jj) {
            int j = tid + jj * 256;
            BT[(size_t)n * 512 + j] = f2bf(Wrel[(size_t)j * NTYP + t]);
        }
        if (tid == 0) bias[n] = 0.f;
    }
}

// ---------------- MFMA GEMM: C[8192][320] = A_gathered[8192][512] @ B -------
__global__ __launch_bounds__(256) void k_gemm(const float* __restrict__ h_grp,
                                              const int* __restrict__ idx,
                                              const int* __restrict__ srcv,
                                              const int* __restrict__ dstv,
                                              const unsigned short* __restrict__ BT,
                                              const float* __restrict__ bias,
                                              float* __restrict__ qk,
                                              float* __restrict__ part) {
    __shared__ __align__(16) unsigned short A[16 * 512];
    __shared__ int ns[16], ss[16], dsv[16];
    int bid = blockIdx.x;
    int swz = (bid & 7) * 64 + (bid >> 3);   // 512 blocks, XCD-chunked
    int m0 = swz * 16;
    int tid = threadIdx.x;
    if (tid < 16) {
        int m = m0 + tid;
        ns[tid] = idx[m];
        ss[tid] = srcv[m];
        dsv[tid] = dstv[m];
    }
    __syncthreads();
    {
        int r = tid >> 4;
        int kc = (tid & 15) * 32;
        const float* src = h_grp +
            ((size_t)ns[r] * LL + (kc < 256 ? ss[r] : dsv[r])) * DH + (kc & 255);
        const float4* s4 = (const float4*)src;
        float4 f[8];
#pragma unroll
        for (int j = 0; j < 8; ++j) f[j] = s4[j];
        unsigned short* Arow = A + r * 512;
#pragma unroll
        for (int j = 0; j < 4; ++j) {
            int c = (kc >> 3) + j;
            int cs = (c & ~7) | ((c & 7) ^ (r & 7));
            unsigned short tmp[8];
            float4 lo = f[j * 2], hi = f[j * 2 + 1];
            tmp[0] = f2bf(lo.x); tmp[1] = f2bf(lo.y);
            tmp[2] = f2bf(lo.z); tmp[3] = f2bf(lo.w);
            tmp[4] = f2bf(hi.x); tmp[5] = f2bf(hi.y);
            tmp[6] = f2bf(hi.z); tmp[7] = f2bf(hi.w);
            *(int4*)(Arow + cs * 8) = *(int4*)tmp;
        }
    }
    __syncthreads();

    int w = tid >> 6, lane = tid & 63;
    int r = lane & 15;
    int q = lane >> 4;
    int n0 = w * 80;
    float4v acc[5];
#pragma unroll
    for (int t = 0; t < 5; ++t) {
        float b = bias[n0 + t * 16 + r];
        acc[t] = (float4v){b, b, b, b};
    }
    const unsigned short* Arow = A + r * 512;
#pragma unroll 2
    for (int ks = 0; ks < 16; ++ks) {
        int c = ks * 4 + q;
        int cs = (c & ~7) | ((c & 7) ^ (r & 7));
        short8v a = *(const short8v*)(Arow + cs * 8);
        int kk = ks * 32 + q * 8;
#pragma unroll
        for (int t = 0; t < 5; ++t) {
            int n = n0 + t * 16 + r;
            short8v b = *(const short8v*)(BT + (size_t)n * 512 + kk);
            acc[t] = __builtin_amdgcn_mfma_f32_16x16x32_bf16(a, b, acc[t], 0, 0, 0);
        }
    }
#pragma unroll
    for (int t = 0; t < 5; ++t) {
        int n = n0 + t * 16 + r;
        if (n < 256) {
#pragma unroll
            for (int j = 0; j < 4; ++j)
                qk[(size_t)(m0 + q * 4 + j) * 256 + n] = acc[t][j];
        } else {
#pragma unroll
            for (int j = 0; j < 4; ++j)
                part[(size_t)(m0 + q * 4 + j) * NTYP + (n - 256)] = acc[t][j];
        }
    }
}

// ---------------- batch list: one record per <=4 queries of same n ----------
__global__ __launch_bounds__(1024) void k_batches(const int* __restrict__ idx,
                                                  int* __restrict__ nbatch,
                                                  int* __restrict__ batch) {
    __shared__ int wsum[16];
    __shared__ int ofs_s[N_SEQ + 1];
    int n = threadIdx.x;
    int lo = 0, hi = MQ;
    while (lo < hi) {
        int mid = (lo + hi) >> 1;
        if (idx[mid] < n) lo = mid + 1; else hi = mid;
    }
    ofs_s[n] = lo;
    if (n == 0) ofs_s[N_SEQ] = MQ;
    __syncthreads();
    int start = ofs_s[n];
    int nq = ofs_s[n + 1] - start;
    int nb = (nq + 3) >> 2;
    int lane = n & 63, w = n >> 6;
    int v = nb;
    for (int off = 1; off < 64; off <<= 1) {
        int t = __shfl_up(v, off);
        if (lane >= off) v += t;
    }
    if (lane == 63) wsum[w] = v;
    __syncthreads();
    if (n < 16) {
        int s = wsum[n];
        for (int off = 1; off < 16; off <<= 1) {
            int t = __shfl_up(s, off);
            if (n >= off) s += t;
        }
        wsum[n] = s;
    }
    __syncthreads();
    int base = (w > 0 ? wsum[w - 1] : 0) + (v - nb);
    for (int b = 0; b < nb; ++b) {
        int ms = start + 4 * b;
        int c = nq - 4 * b; if (c > 4) c = 4;
        batch[base + b] = ms | (c << 16);
    }
    if (n == N_SEQ - 1) nbatch[0] = base + nb;
}

// ---------------- attention: one wave per 4-query batch (shared n) ----------
__global__ __launch_bounds__(256) void k_attn5(const float* __restrict__ h_grp,
                                               const int* __restrict__ idx,
                                               const int* __restrict__ pos2grp,
                                               const int* __restrict__ msk,
                                               const float* __restrict__ zw,
                                               const float* __restrict__ qk,
                                               const float* __restrict__ part,
                                               const float* __restrict__ brel,
                                               const int* __restrict__ nbatch,
                                               const int* __restrict__ batch,
                                               float* __restrict__ out) {
    __shared__ float attn_lds[4][4][68];
    int nb = nbatch[0];
    int cpx = (nb + 7) >> 3;                 // batches per XCD chunk
    int wv = blockIdx.x * 4 + (threadIdx.x >> 6);
    int y = wv >> 3;
    if (y >= cpx) return;
    int swz = (wv & 7) * cpx + y;
    if (swz >= nb) return;
    int rec = batch[swz];
    int m0 = rec & 0xFFFF;
    int cnt = rec >> 16;
    int w = threadIdx.x >> 6;
    int lane = threadIdx.x & 63;
    int n = idx[m0];
    int j = lane & 15, g = lane >> 4;

    float4 qv[4][4];
#pragma unroll
    for (int i = 0; i < 4; ++i) {
        int mi = m0 + (i < cnt ? i : cnt - 1);
        const float4* qk4 = (const float4*)(qk + (size_t)mi * 256);
        qv[i][0] = qk4[j];
        qv[i][1] = qk4[j + 16];
        qv[i][2] = qk4[j + 32];
        qv[i][3] = qk4[j + 48];
    }
    int m_all = msk[n * LL + lane];
    int g_all = pos2grp[n * LL + lane];

    const float* hb = h_grp + (size_t)n * LL * DH + (size_t)g * 16 * DH;
    float vr[16];
#pragma unroll
    for (int r = 0; r < 16; ++r) {
        const float4* hr = (const float4*)(hb + r * DH);
        float4 h0 = hr[j], h1 = hr[j + 16], h2 = hr[j + 32], h3 = hr[j + 48];
        float p[4];
#pragma unroll
        for (int i = 0; i < 4; ++i) {
            p[i] = h0.x * qv[i][0].x + h0.y * qv[i][0].y + h0.z * qv[i][0].z + h0.w * qv[i][0].w
                 + h1.x * qv[i][1].x + h1.y * qv[i][1].y + h1.z * qv[i][1].z + h1.w * qv[i][1].w
                 + h2.x * qv[i][2].x + h2.y * qv[i][2].y + h2.z * qv[i][2].z + h2.w * qv[i][2].w
                 + h3.x * qv[i][3].x + h3.y * qv[i][3].y + h3.z * qv[i][3].z + h3.w * qv[i][3].w;
        }
        // multi-value butterfly: fold 4 queries while reducing 16 lanes
        float tA = (lane & 1) ? p[0] : p[1];
        tA = __shfl_xor(tA, 1);
        float u01 = ((lane & 1) ? p[1] : p[0]) + tA;
        float tB = (lane & 1) ? p[2] : p[3];
        tB = __shfl_xor(tB, 1);
        float u23 = ((lane & 1) ? p[3] : p[2]) + tB;
        float tC = (lane & 2) ? u01 : u23;
        tC = __shfl_xor(tC, 2);
        float v = ((lane & 2) ? u23 : u01) + tC;
        v += __shfl_xor(v, 4);
        v += __shfl_xor(v, 8);
        // lane now holds row (16g+r) score for query (lane&3)
        int mk = __shfl(m_all, (lane & 48) + r);
        vr[r] = mk ? v * (1.0f / 16.0f) : -INFINITY;
    }
    // per-query softmax: lane owns rows of its group for query lane&3
    float mx = vr[0];
#pragma unroll
    for (int r = 1; r < 16; ++r) mx = fmaxf(mx, vr[r]);
    mx = fmaxf(mx, __shfl_xor(mx, 16));
    mx = fmaxf(mx, __shfl_xor(mx, 32));
    float sum = 0.f;
#pragma unroll
    for (int r = 0; r < 16; ++r) {
        vr[r] = __expf(vr[r] - mx);
        sum += vr[r];
    }
    sum += __shfl_xor(sum, 16);
    sum += __shfl_xor(sum, 32);
    float inv = 1.0f / sum;
    // lanes j<4 (one per (query=j, group g)) store attn rows to LDS
    if (j < 4) {
        float4* dst = (float4*)&attn_lds[w][j][g * 16];
#pragma unroll
        for (int k = 0; k < 4; ++k) {
            float4 t4;
            t4.x = vr[k * 4 + 0] * inv;
            t4.y = vr[k * 4 + 1] * inv;
            t4.z = vr[k * 4 + 2] * inv;
            t4.w = vr[k * 4 + 3] * inv;
            dst[k] = t4;
        }
    }
    float a[4];
#pragma unroll
    for (int i = 0; i < 4; ++i) a[i] = attn_lds[w][i][lane];

    float acc[4] = {0.f, 0.f, 0.f, 0.f};
#pragma unroll
    for (int l = 0; l < 64; ++l) {
        int gl = __builtin_amdgcn_readlane(g_all, l);
        float zr = zw[(size_t)gl * NTYP + lane];
#pragma unroll
        for (int i = 0; i < 4; ++i)
            acc[i] += bcast(a[i], l) * zr;
    }
    float bv = brel[lane];
    for (int i = 0; i < cnt; ++i) {
        int mi = m0 + i;
        out[(size_t)mi * NTYP + lane] = part[(size_t)mi * NTYP + lane] + bv + acc[i];
    }
}

extern "C" void kernel_launch(void* const* d_in, const int* in_sizes, int n_in,
                              void* d_out, int out_size, void* d_ws, size_t ws_size,
                              hipStream_t stream) {
    const int*   mem     = (const int*)d_in[0];
    const int*   grp     = (const int*)d_in[1];
    const int*   pos2grp = (const int*)d_in[2];
    const float* h_grp   = (const float*)d_in[3];
    const int*   msk     = (const int*)d_in[4];
    const int*   idx     = (const int*)d_in[5];
    const int*   srcv    = (const int*)d_in[6];
    const int*   dstv    = (const int*)d_in[7];
    // d_in[8] = typ (unused by the reference)
    const float* tok_emb = (const float*)d_in[9];
    const float* Wq      = (const float*)d_in[10];
    const float* bq      = (const float*)d_in[11];
    const float* Wk      = (const float*)d_in[12];
    const float* bk      = (const float*)d_in[13];  // softmax-invariant: unused
    const float* Wrel    = (const float*)d_in[14];
    const float* brel    = (const float*)d_in[15];
    float* out = (float*)d_out;
    (void)bk;

    float* ws = (float*)d_ws;
    size_t off = 0;
    float* zw   = ws + off; off += (size_t)GG * NTYP;       // 262144
    float* qk   = ws + off; off += (size_t)MQ * 256;        // 2097152
    float* part = ws + off; off += (size_t)MQ * NTYP;       // 524288
    float* bias = ws + off; off += 320;
    unsigned short* BT = (unsigned short*)(ws + off); off += (320 * 512) / 2;
    int* cnt        = (int*)(ws + off); off += GG;
    int* ofs        = (int*)(ws + off); off += GG;
    int* cur        = (int*)(ws + off); off += GG;
    int* tok_sorted = (int*)(ws + off); off += NMEM;
    int* nbatch     = (int*)(ws + off); off += 4;
    int* batch      = (int*)(ws + off); off += 3072;

    // segment-sum via counting sort (no float atomics), fused zw projection
    hipMemsetAsync(cnt, 0, GG * sizeof(int), stream);
    k_hist<<<NMEM / 256, 256, 0, stream>>>(grp, cnt);
    k_scan<<<1, 1024, 0, stream>>>(cnt, ofs, cur);
    k_permute<<<NMEM / 256, 256, 0, stream>>>(grp, mem, cur, tok_sorted);
    k_zsum<<<GG, 128, 0, stream>>>(ofs, cnt, tok_sorted, tok_emb, Wrel, zw);

    // batch list (n-sorted, deterministic)
    k_batches<<<1, 1024, 0, stream>>>(idx, nbatch, batch);

    // folded weights -> bf16 B^T [320][512] + bias[320]
    k_wqkb<<<320, 256, 0, stream>>>(Wq, bq, Wk, Wrel, BT, bias);

    // MFMA GEMM: qk (256 cols) + logit partial (64 cols)
    k_gemm<<<MQ / 16, 256, 0, stream>>>(h_grp, idx, srcv, dstv, BT, bias, qk, part);

    // one wave per 4-query batch
    k_attn5<<<768, 256, 0, stream>>>(h_grp, idx, pos2grp, msk, zw, qk, part, brel,
                                     nbatch, batch, out);
}

// Round 8
// 145.830 us; speedup vs baseline: 1.1110x; 1.1110x over previous
//
#include <hip/hip_runtime.h>
#include <math.h>

#define N_SEQ 1024
#define LL 64
#define DH 256
#define DX 128
#define MQ 8192
#define GG 4096
#define NTYP 64
#define NMEM 262144

typedef __attribute__((ext_vector_type(8))) short short8v;
typedef __attribute__((ext_vector_type(4))) float float4v;

__device__ __forceinline__ float bcast(float v, int l) {
    return __uint_as_float(__builtin_amdgcn_readlane(__float_as_uint(v), l));
}

__device__ __forceinline__ unsigned short f2bf(float x) {
    unsigned int u = __float_as_uint(x);
    u += 0x7FFFu + ((u >> 16) & 1u);   // round-to-nearest-even
    return (unsigned short)(u >> 16);
}

// ---------------- counting-sort based segment sum ---------------------------
__global__ __launch_bounds__(256) void k_hist(const int* __restrict__ grp,
                                              int* __restrict__ cnt) {
    int i = blockIdx.x * 256 + threadIdx.x;
    if (i < NMEM) atomicAdd(&cnt[grp[i]], 1);
}

__global__ __launch_bounds__(1024) void k_scan(const int* __restrict__ cnt,
                                               int* __restrict__ ofs,
                                               int* __restrict__ cur) {
    __shared__ int wsum[16];
    int tid = threadIdx.x;
    int4 c = ((const int4*)cnt)[tid];
    int local = c.x + c.y + c.z + c.w;
    int lane = tid & 63, w = tid >> 6;
    int v = local;
    for (int off = 1; off < 64; off <<= 1) {
        int t = __shfl_up(v, off);
        if (lane >= off) v += t;
    }
    if (lane == 63) wsum[w] = v;
    __syncthreads();
    if (tid < 16) {
        int s = wsum[tid];
        for (int off = 1; off < 16; off <<= 1) {
            int t = __shfl_up(s, off);
            if (tid >= off) s += t;
        }
        wsum[tid] = s;
    }
    __syncthreads();
    int base = (w > 0 ? wsum[w - 1] : 0) + (v - local);
    int4 o;
    o.x = base;
    o.y = base + c.x;
    o.z = o.y + c.y;
    o.w = o.z + c.z;
    ((int4*)ofs)[tid] = o;
    ((int4*)cur)[tid] = o;
}

__global__ __launch_bounds__(256) void k_permute(const int* __restrict__ grp,
                                                 const int* __restrict__ mem,
                                                 int* __restrict__ cur,
                                                 int* __restrict__ tok_sorted) {
    int i = blockIdx.x * 256 + threadIdx.x;
    if (i < NMEM) {
        int g = grp[i];
        int pos = atomicAdd(&cur[g], 1);
        tok_sorted[pos] = mem[i];
    }
}

// z[g] = sum tok_emb rows; fused: zw[g] = z[g] @ Wrel[512:640]
__global__ __launch_bounds__(128) void k_zsum(const int* __restrict__ ofs,
                                              const int* __restrict__ cnt,
                                              const int* __restrict__ tok_sorted,
                                              const float* __restrict__ tok_emb,
                                              const float* __restrict__ Wrel,
                                              float* __restrict__ zw) {
    __shared__ int idxs[128];
    __shared__ float zs[128];
    int g = blockIdx.x;
    int tid = threadIdx.x;
    int start = ofs[g], n = cnt[g];
    float a0 = 0.f, a1 = 0.f, a2 = 0.f, a3 = 0.f;
    for (int j0 = 0; j0 < n; j0 += 128) {
        __syncthreads();
        int rem = n - j0;
        if (tid < rem) idxs[tid] = tok_sorted[start + j0 + tid];
        __syncthreads();
        int kmax = rem < 128 ? rem : 128;
        int k = 0;
        for (; k + 3 < kmax; k += 4) {
            a0 += tok_emb[(size_t)idxs[k + 0] * DX + tid];
            a1 += tok_emb[(size_t)idxs[k + 1] * DX + tid];
            a2 += tok_emb[(size_t)idxs[k + 2] * DX + tid];
            a3 += tok_emb[(size_t)idxs[k + 3] * DX + tid];
        }
        for (; k < kmax; ++k)
            a0 += tok_emb[(size_t)idxs[k] * DX + tid];
    }
    zs[tid] = (a0 + a1) + (a2 + a3);
    __syncthreads();
    if (tid < NTYP) {
        float a2s = 0.f;
#pragma unroll 8
        for (int v = 0; v < DX; ++v)
            a2s += zs[v] * Wrel[(size_t)(512 + v) * NTYP + tid];
        zw[(size_t)g * NTYP + tid] = a2s;
    }
}

// ---------------- build BT[320][512] bf16 and bias[320] ---------------------
__global__ __launch_bounds__(256) void k_wqkb(const float* __restrict__ Wq,
                                              const float* __restrict__ bq,
                                              const float* __restrict__ Wk,
                                              const float* __restrict__ Wrel,
                                              unsigned short* __restrict__ BT,
                                              float* __restrict__ bias) {
    int n = blockIdx.x;
    int tid = threadIdx.x;
    if (n < 256) {
        __shared__ float wk_s[256];
        __shared__ float red[4];
        wk_s[tid] = Wk[(size_t)n * 256 + tid];
        __syncthreads();
#pragma unroll
        for (int jj = 0; jj < 2; ++jj) {
            int j = tid + jj * 256;
            const float* wq = Wq + (size_t)j * 256;
            float acc = 0.f;
#pragma unroll 4
            for (int e = 0; e < 256; ++e) acc += wq[e] * wk_s[e];
            BT[(size_t)n * 512 + j] = f2bf(acc);
        }
        float p = wk_s[tid] * bq[tid];
        for (int o = 32; o; o >>= 1) p += __shfl_xor(p, o);
        if ((tid & 63) == 0) red[tid >> 6] = p;
        __syncthreads();
        if (tid == 0) bias[n] = red[0] + red[1] + red[2] + red[3];
    } else {
        int t = n - 256;
#pragma unroll
        for (int jj = 0; jj < 2; ++jj) {
            int j = tid + jj * 256;
            BT[(size_t)n * 512 + j] = f2bf(Wrel[(size_t)j * NTYP + t]);
        }
        if (tid == 0) bias[n] = 0.f;
    }
}

// ---------------- MFMA GEMM: C[8192][320] = A_gathered[8192][512] @ B -------
__global__ __launch_bounds__(256) void k_gemm(const float* __restrict__ h_grp,
                                              const int* __restrict__ idx,
                                              const int* __restrict__ srcv,
                                              const int* __restrict__ dstv,
                                              const unsigned short* __restrict__ BT,
                                              const float* __restrict__ bias,
                                              float* __restrict__ qk,
                                              float* __restrict__ part) {
    __shared__ __align__(16) unsigned short A[16 * 512];
    __shared__ int ns[16], ss[16], dsv[16];
    int bid = blockIdx.x;
    int swz = (bid & 7) * 64 + (bid >> 3);   // 512 blocks, XCD-chunked
    int m0 = swz * 16;
    int tid = threadIdx.x;
    if (tid < 16) {
        int m = m0 + tid;
        ns[tid] = idx[m];
        ss[tid] = srcv[m];
        dsv[tid] = dstv[m];
    }
    __syncthreads();
    {
        int r = tid >> 4;
        int kc = (tid & 15) * 32;
        const float* src = h_grp +
            ((size_t)ns[r] * LL + (kc < 256 ? ss[r] : dsv[r])) * DH + (kc & 255);
        const float4* s4 = (const float4*)src;
        float4 f[8];
#pragma unroll
        for (int j = 0; j < 8; ++j) f[j] = s4[j];
        unsigned short* Arow = A + r * 512;
#pragma unroll
        for (int j = 0; j < 4; ++j) {
            int c = (kc >> 3) + j;
            int cs = (c & ~7) | ((c & 7) ^ (r & 7));
            unsigned short tmp[8];
            float4 lo = f[j * 2], hi = f[j * 2 + 1];
            tmp[0] = f2bf(lo.x); tmp[1] = f2bf(lo.y);
            tmp[2] = f2bf(lo.z); tmp[3] = f2bf(lo.w);
            tmp[4] = f2bf(hi.x); tmp[5] = f2bf(hi.y);
            tmp[6] = f2bf(hi.z); tmp[7] = f2bf(hi.w);
            *(int4*)(Arow + cs * 8) = *(int4*)tmp;
        }
    }
    __syncthreads();

    int w = tid >> 6, lane = tid & 63;
    int r = lane & 15;
    int q = lane >> 4;
    int n0 = w * 80;
    float4v acc[5];
#pragma unroll
    for (int t = 0; t < 5; ++t) {
        float b = bias[n0 + t * 16 + r];
        acc[t] = (float4v){b, b, b, b};
    }
    const unsigned short* Arow = A + r * 512;
#pragma unroll 2
    for (int ks = 0; ks < 16; ++ks) {
        int c = ks * 4 + q;
        int cs = (c & ~7) | ((c & 7) ^ (r & 7));
        short8v a = *(const short8v*)(Arow + cs * 8);
        int kk = ks * 32 + q * 8;
#pragma unroll
        for (int t = 0; t < 5; ++t) {
            int n = n0 + t * 16 + r;
            short8v b = *(const short8v*)(BT + (size_t)n * 512 + kk);
            acc[t] = __builtin_amdgcn_mfma_f32_16x16x32_bf16(a, b, acc[t], 0, 0, 0);
        }
    }
#pragma unroll
    for (int t = 0; t < 5; ++t) {
        int n = n0 + t * 16 + r;
        if (n < 256) {
#pragma unroll
            for (int j = 0; j < 4; ++j)
                qk[(size_t)(m0 + q * 4 + j) * 256 + n] = acc[t][j];
        } else {
#pragma unroll
            for (int j = 0; j < 4; ++j)
                part[(size_t)(m0 + q * 4 + j) * NTYP + (n - 256)] = acc[t][j];
        }
    }
}

// ---------------- attention: one block (2 waves) per query ------------------
// wave w owns rows 32w..32w+31 (8 rows per 16-lane group); butterfly fold.
__global__ __launch_bounds__(128) void k_attn6(const float* __restrict__ h_grp,
                                               const int* __restrict__ idx,
                                               const int* __restrict__ pos2grp,
                                               const int* __restrict__ msk,
                                               const float* __restrict__ zw,
                                               const float* __restrict__ qk,
                                               const float* __restrict__ part,
                                               const float* __restrict__ brel,
                                               float* __restrict__ out) {
    __shared__ float s_lds[LL];
    __shared__ float ctx_lds[2][NTYP];
    int bid = blockIdx.x;
    int m = (bid & 7) * 1024 + (bid >> 3);   // XCD-chunked over 8192 blocks
    int w = threadIdx.x >> 6;
    int lane = threadIdx.x & 63;
    int n = idx[m];
    int j = lane & 15;
    int gr = lane >> 4;

    const float4* qk4 = (const float4*)(qk + (size_t)m * 256);
    float4 qv0 = qk4[j];
    float4 qv1 = qk4[j + 16];
    float4 qv2 = qk4[j + 32];
    float4 qv3 = qk4[j + 48];

    int m_all = msk[n * LL + lane];
    int g_all = pos2grp[n * LL + lane];

    // 8 rows per lane-group: p[r] = partial dot over this lane's 16 columns
    const float* hb = h_grp + ((size_t)n * LL + 32 * w + 8 * gr) * DH;
    float p[8];
#pragma unroll
    for (int r = 0; r < 8; ++r) {
        const float4* hr = (const float4*)(hb + r * DH);
        float4 h0 = hr[j], h1 = hr[j + 16], h2 = hr[j + 32], h3 = hr[j + 48];
        p[r] = h0.x * qv0.x + h0.y * qv0.y + h0.z * qv0.z + h0.w * qv0.w
             + h1.x * qv1.x + h1.y * qv1.y + h1.z * qv1.z + h1.w * qv1.w
             + h2.x * qv2.x + h2.y * qv2.y + h2.z * qv2.z + h2.w * qv2.w
             + h3.x * qv3.x + h3.y * qv3.y + h3.z * qv3.z + h3.w * qv3.w;
    }
    // breadth-first multi-value fold: 8 shfls, depth 4
    float a[4];
#pragma unroll
    for (int r = 0; r < 4; ++r) {
        float keep = (j & 8) ? p[r + 4] : p[r];
        float send = (j & 8) ? p[r] : p[r + 4];
        a[r] = keep + __shfl_xor(send, 8);
    }
    float b0, b1;
    {
        float k0 = (j & 4) ? a[2] : a[0];
        float s0 = (j & 4) ? a[0] : a[2];
        b0 = k0 + __shfl_xor(s0, 4);
        float k1 = (j & 4) ? a[3] : a[1];
        float s1 = (j & 4) ? a[1] : a[3];
        b1 = k1 + __shfl_xor(s1, 4);
    }
    float c;
    {
        float k = (j & 2) ? b1 : b0;
        float s = (j & 2) ? b0 : b1;
        c = k + __shfl_xor(s, 2);
    }
    c += __shfl_xor(c, 1);
    // lane j holds rowsum of global row: 32w + 8gr + (j>>1)  (dup over j&1)
    int grow = 32 * w + 8 * gr + (j >> 1);
    int mk = __shfl(m_all, grow);
    float sv = mk ? c * (1.0f / 16.0f) : -INFINITY;
    if ((j & 1) == 0) s_lds[grow] = sv;
    __syncthreads();

    // full softmax, redundantly per wave
    float s = s_lds[lane];
    float mx = s;
    for (int o = 32; o; o >>= 1) mx = fmaxf(mx, __shfl_xor(mx, o));
    float pe = __expf(s - mx);            // -inf rows -> 0
    float sum = pe;
    for (int o = 32; o; o >>= 1) sum += __shfl_xor(sum, o);
    float attn = pe / sum;

    // ctx half: wave w sums l in [32w, 32w+32)
    float acc = 0.f;
#pragma unroll 8
    for (int l0 = 0; l0 < 32; ++l0) {
        int l = 32 * w + l0;
        float al = bcast(attn, l);
        int gl = __builtin_amdgcn_readlane(g_all, l);
        acc += al * zw[(size_t)gl * NTYP + lane];
    }
    ctx_lds[w][lane] = acc;
    __syncthreads();
    if (w == 0) {
        float tot = acc + ctx_lds[1][lane];
        out[(size_t)m * NTYP + lane] =
            part[(size_t)m * NTYP + lane] + brel[lane] + tot;
    }
}

extern "C" void kernel_launch(void* const* d_in, const int* in_sizes, int n_in,
                              void* d_out, int out_size, void* d_ws, size_t ws_size,
                              hipStream_t stream) {
    const int*   mem     = (const int*)d_in[0];
    const int*   grp     = (const int*)d_in[1];
    const int*   pos2grp = (const int*)d_in[2];
    const float* h_grp   = (const float*)d_in[3];
    const int*   msk     = (const int*)d_in[4];
    const int*   idx     = (const int*)d_in[5];
    const int*   srcv    = (const int*)d_in[6];
    const int*   dstv    = (const int*)d_in[7];
    // d_in[8] = typ (unused by the reference)
    const float* tok_emb = (const float*)d_in[9];
    const float* Wq      = (const float*)d_in[10];
    const float* bq      = (const float*)d_in[11];
    const float* Wk      = (const float*)d_in[12];
    const float* bk      = (const float*)d_in[13];  // softmax-invariant: unused
    const float* Wrel    = (const float*)d_in[14];
    const float* brel    = (const float*)d_in[15];
    float* out = (float*)d_out;
    (void)bk;

    float* ws = (float*)d_ws;
    size_t off = 0;
    float* zw   = ws + off; off += (size_t)GG * NTYP;       // 262144
    float* qk   = ws + off; off += (size_t)MQ * 256;        // 2097152
    float* part = ws + off; off += (size_t)MQ * NTYP;       // 524288
    float* bias = ws + off; off += 320;
    unsigned short* BT = (unsigned short*)(ws + off); off += (320 * 512) / 2;
    int* cnt        = (int*)(ws + off); off += GG;
    int* ofs        = (int*)(ws + off); off += GG;
    int* cur        = (int*)(ws + off); off += GG;
    int* tok_sorted = (int*)(ws + off); off += NMEM;

    // segment-sum via counting sort (no float atomics), fused zw projection
    hipMemsetAsync(cnt, 0, GG * sizeof(int), stream);
    k_hist<<<NMEM / 256, 256, 0, stream>>>(grp, cnt);
    k_scan<<<1, 1024, 0, stream>>>(cnt, ofs, cur);
    k_permute<<<NMEM / 256, 256, 0, stream>>>(grp, mem, cur, tok_sorted);
    k_zsum<<<GG, 128, 0, stream>>>(ofs, cnt, tok_sorted, tok_emb, Wrel, zw);

    // folded weights -> bf16 B^T [320][512] + bias[320]
    k_wqkb<<<320, 256, 0, stream>>>(Wq, bq, Wk, Wrel, BT, bias);

    // MFMA GEMM: qk (256 cols) + logit partial (64 cols)
    k_gemm<<<MQ / 16, 256, 0, stream>>>(h_grp, idx, srcv, dstv, BT, bias, qk, part);

    // one block (2 waves) per query
    k_attn6<<<MQ, 128, 0, stream>>>(h_grp, idx, pos2grp, msk, zw, qk, part, brel, out);
}